// Round 3
// baseline (5544.744 us; speedup 1.0000x reference)
//
#include <hip/hip_runtime.h>
#include <math.h>

// V=50000, E=300, H=128, L=32, B=8; gates = 8H = 1024 wide; cell state = 2H = 256.
// 256 blocks x 256 threads, PLAIN launch (no cooperative — it silently fails in
// this harness). Grid sync = hand-rolled monotonic-counter barrier in d_ws,
// which the harness poisons to 0xAAAAAAAA before every launch.
// Block = (s_slot 0..31 cell slot) x (chunk 0..7).
// Per-diagonal: phase A (gates GEMM, W_hh chunk register-resident) -> barrier
//            -> phase B (elementwise + condense)                   -> barrier

// ---------------- workspace layout (floats) ----------------
#define P_OFF     0            // Pproj [32][8][1024]  (includes b_ih+b_hh)
#define HYP_OFF   262144       // Hypproj [32][8][1024]
#define GATES_OFF 524288       // Gates [32 slots][8][1024]
#define HN0_OFF   786432       // Hn buf0 [32][8][128]
#define HN1_OFF   819200
#define CN0_OFF   851968
#define CN1_OFF   884736
#define BAR_OFF   917504       // unsigned barrier counter (poison = 0xAAAAAAAA)

#define BAR_BASE 0xAAAAAAAAu

__device__ __forceinline__ float sigm(float x) { return 1.f / (1.f + __expf(-x)); }
__device__ __forceinline__ float tanh_fast(float x) { return 1.f - 2.f / (__expf(2.f * x) + 1.f); }

__device__ __forceinline__ void grid_barrier(unsigned* bar, unsigned k) {
    __threadfence();            // release: drain + make stores agent-visible
    __syncthreads();
    if (threadIdx.x == 0) {
        atomicAdd(bar, 1u);     // device-scope by default
        const unsigned target = k * 256u;
        long spins = 0;
        while ((__hip_atomic_load(bar, __ATOMIC_RELAXED, __HIP_MEMORY_SCOPE_AGENT)
                - BAR_BASE) < target) {
            __builtin_amdgcn_s_sleep(1);
            if (++spins > (1L << 26)) break;   // failsafe: wrong answer > hang
        }
        __threadfence();        // acquire: invalidate stale L1/L2 lines
    }
    __syncthreads();
}

__global__ void __launch_bounds__(256, 1) grid_lstm_kernel(
    const int* __restrict__ premise, const int* __restrict__ hypothesis,
    const float* __restrict__ emb,
    const float* __restrict__ W_ih, const float* __restrict__ b_ih,
    const float* __restrict__ W_hh, const float* __restrict__ b_hh,
    const float* __restrict__ W_ch, const float* __restrict__ b_ch,
    const float* __restrict__ W_cc, const float* __restrict__ b_cc,
    const float* __restrict__ W1, const float* __restrict__ b1,
    const float* __restrict__ W2, const float* __restrict__ b2,
    const float* __restrict__ W3, const float* __restrict__ b3,
    float* __restrict__ out, float* __restrict__ ws)
{
    __shared__ float hin[8 * 256];     // h_in staging [8][256]
    __shared__ float scratch[4352];    // red[256][17] / phaseB [2][8][256] / emb / MLP

    const int tid = threadIdx.x;
    const int bid = blockIdx.x;

    float* Pproj   = ws + P_OFF;
    float* Hypproj = ws + HYP_OFF;
    float* Gates   = ws + GATES_OFF;
    float* HnB[2]  = { ws + HN0_OFF, ws + HN1_OFF };
    float* CnB[2]  = { ws + CN0_OFF, ws + CN1_OFF };
    unsigned* bar  = (unsigned*)(ws + BAR_OFF);
    unsigned barK  = 0;

    const int s_slot = bid >> 3;   // 0..31 cell slot
    const int chunk  = bid & 7;    // 0..7 gate chunk (A) / row part (B)

    // ---- Phase 0: input projections. 256 blocks = 64 (side,pos) units x 4 quarters.
    {
        const int unit = bid >> 2, q = bid & 3;
        const int side = unit >> 5, pos = unit & 31;
        const int* toks = side ? hypothesis : premise;
        float* est = scratch;  // [8][300]
        for (int idx = tid; idx < 8 * 300; idx += 256) {
            int b = idx / 300, e = idx - b * 300;
            est[idx] = emb[(long)toks[b * 32 + pos] * 300 + e];
        }
        __syncthreads();
        const int g = q * 256 + tid;
        float acc0[8];
        const float bias = side ? 0.f : (b_ih[g] + b_hh[g]);
        #pragma unroll
        for (int b = 0; b < 8; b++) acc0[b] = bias;
        const float* wr = W_ih + (long)g * 600 + side * 300;
        for (int e = 0; e < 300; e += 4) {
            float4 w = *(const float4*)(wr + e);
            #pragma unroll
            for (int b = 0; b < 8; b++) {
                const float* eb = est + b * 300 + e;
                acc0[b] += w.x * eb[0] + w.y * eb[1] + w.z * eb[2] + w.w * eb[3];
            }
        }
        float* dstbase = (side ? Hypproj : Pproj) + pos * 8192;
        #pragma unroll
        for (int b = 0; b < 8; b++) dstbase[b * 1024 + g] = acc0[b];
    }
    grid_barrier(bar, ++barK);

    // ---- Load this block's W_hh chunk into REGISTERS (once).
    // Thread (gg = tid&31, ks = tid>>5) holds gate rows chunk*128 + gg*4 + a (a=0..3),
    // k in [ks*32, ks*32+32): w[a][c] = W_hh[row][ks*32 + c*4 .. +3].
    const int gg = tid & 31, ks = tid >> 5;
    float4 w[4][8];
    #pragma unroll
    for (int a = 0; a < 4; a++) {
        const float* wrow = W_hh + (chunk * 128 + gg * 4 + a) * 256 + ks * 32;
        #pragma unroll
        for (int c = 0; c < 8; c++) w[a][c] = *(const float4*)(wrow + c * 4);
    }

    // ---- Wavefront over anti-diagonals ----
    #pragma unroll 1
    for (int d = 0; d < 63; d++) {
        const int i0 = (d > 31) ? (d - 31) : 0;
        const int nc = ((d < 62 - d) ? d : 62 - d) + 1;
        const float* HnP = HnB[(d + 1) & 1];
        float*       HnC = HnB[d & 1];
        const float* CnP = CnB[(d + 1) & 1];
        float*       CnC = CnB[d & 1];

        // ================= Phase A: gates GEMM =================
        if (s_slot < nc) {
            const int i = i0 + s_slot, j = d - i;
            // stage h_in = [h_up(128) ; h_left(128)] for 8 batches
            #pragma unroll
            for (int rep = 0; rep < 8; rep++) {
                int idx = rep * 256 + tid;
                int b = idx >> 8, k = idx & 255;
                float v = 0.f;
                if (k < 128) { if (i > 0) v = HnP[(i - 1) * 1024 + b * 128 + k]; }
                else         { if (j > 0) v = HnP[i * 1024 + b * 128 + (k - 128)]; }
                hin[idx] = v;
            }
            __syncthreads();
            const float* hb = hin + ks * 32;
            float acc[4][8];
            #pragma unroll
            for (int a = 0; a < 4; a++)
                #pragma unroll
                for (int b = 0; b < 8; b++) acc[a][b] = 0.f;
            #pragma unroll
            for (int c = 0; c < 8; c++) {
                #pragma unroll
                for (int b = 0; b < 8; b++) {
                    float4 h = *(const float4*)(hb + b * 256 + c * 4);
                    #pragma unroll
                    for (int a = 0; a < 4; a++)
                        acc[a][b] += w[a][c].x * h.x + w[a][c].y * h.y
                                   + w[a][c].z * h.z + w[a][c].w * h.w;
                }
            }
            // reduce across the 8 K-segs, two halves through LDS (red[256][17])
            float* red = scratch;
            #pragma unroll 1
            for (int half = 0; half < 2; half++) {
                __syncthreads();
                #pragma unroll
                for (int a = 0; a < 2; a++)
                    #pragma unroll
                    for (int b = 0; b < 8; b++)
                        red[tid * 17 + a * 8 + b] = acc[half * 2 + a][b];
                __syncthreads();
                if (tid < 32) {
                    for (int a = 0; a < 2; a++) {
                        const int gs = half * 2 + a;
                        const int g = chunk * 128 + tid * 4 + gs;
                        for (int b = 0; b < 8; b++) {
                            float sum = 0.f;
                            #pragma unroll
                            for (int k2 = 0; k2 < 8; k2++)
                                sum += red[(tid + 32 * k2) * 17 + a * 8 + b];
                            sum += Pproj[i * 8192 + b * 1024 + g]
                                 + Hypproj[j * 8192 + b * 1024 + g];
                            Gates[s_slot * 8192 + b * 1024 + g] = sum;
                        }
                    }
                }
            }
        }
        grid_barrier(bar, ++barK);

        // ================= Phase B: elementwise + condense =================
        if (s_slot < nc) {
            const int i = i0 + s_slot, j = d - i;
            float* stc = scratch;          // c_new [8][256]
            float* sth = scratch + 2048;   // h_new [8][256]
            const float* Gs = Gates + s_slot * 8192;
            #pragma unroll
            for (int rep = 0; rep < 8; rep++) {
                int idx = rep * 256 + tid;
                int b = idx >> 8, t = idx & 255;
                float gi = Gs[b * 1024 + t];
                float gf = Gs[b * 1024 + 256 + t];
                float gc = Gs[b * 1024 + 512 + t];
                float go = Gs[b * 1024 + 768 + t];
                float cin = 0.f;
                if (t < 128) { if (i > 0) cin = CnP[(i - 1) * 1024 + b * 128 + t]; }
                else         { if (j > 0) cin = CnP[i * 1024 + b * 128 + (t - 128)]; }
                float cn = sigm(gf) * cin + sigm(gi) * tanh_fast(gc);
                float hn = sigm(go) * tanh_fast(cn);
                stc[idx] = cn;
                sth[idx] = hn;
            }
            __syncthreads();
            {
                const int r = tid & 31, b = tid >> 5;
                const int row = chunk * 16 + (r & 15);
                const float* src; const float* Wm; float bias; float* dst;
                if (r < 16) { src = sth; Wm = W_ch; bias = b_ch[row]; dst = HnC + i * 1024 + b * 128 + row; }
                else        { src = stc; Wm = W_cc; bias = b_cc[row]; dst = CnC + i * 1024 + b * 128 + row; }
                const float* wrow = Wm + row * 256;
                const float* x = src + b * 256;
                float a2 = bias;
                for (int k = 0; k < 256; k += 4) {
                    float4 wv = *(const float4*)(wrow + k);
                    float4 xv = *(const float4*)(x + k);
                    a2 += wv.x * xv.x + wv.y * xv.y + wv.z * xv.z + wv.w * xv.w;
                }
                *dst = a2;
            }
        }
        grid_barrier(bar, ++barK);
    }

    // ---- Final MLP + softmax on corner state (cell 31,31 on diag 62 -> HnB[0]) ----
    if (bid == 0) {
        const float* hsrc = HnB[0] + 31 * 1024;   // [8][128]
        float* s1 = scratch;
        float* s2 = scratch + 1024;
        for (int idx = tid; idx < 1024; idx += 256) s1[idx] = hsrc[idx];
        __syncthreads();
        for (int idx = tid; idx < 1024; idx += 256) {
            int b = idx >> 7, o = idx & 127;
            float a = b1[o];
            const float* wr = W1 + o * 128; const float* x = s1 + b * 128;
            for (int k = 0; k < 128; k++) a += wr[k] * x[k];
            s2[idx] = fmaxf(a, 0.f);
        }
        __syncthreads();
        for (int idx = tid; idx < 1024; idx += 256) {
            int b = idx >> 7, o = idx & 127;
            float a = b2[o];
            const float* wr = W2 + o * 128; const float* x = s2 + b * 128;
            for (int k = 0; k < 128; k++) a += wr[k] * x[k];
            s1[idx] = fmaxf(a, 0.f);
        }
        __syncthreads();
        if (tid < 8) {
            const int b = tid;
            float lg[3];
            for (int c = 0; c < 3; c++) {
                float a = b3[c];
                const float* wr = W3 + c * 128; const float* x = s1 + b * 128;
                for (int k = 0; k < 128; k++) a += wr[k] * x[k];
                lg[c] = a;
            }
            float m = fmaxf(lg[0], fmaxf(lg[1], lg[2]));
            float e0 = expf(lg[0] - m), e1 = expf(lg[1] - m), e2 = expf(lg[2] - m);
            float s = e0 + e1 + e2;
            out[b * 3 + 0] = e0 / s;
            out[b * 3 + 1] = e1 / s;
            out[b * 3 + 2] = e2 / s;
        }
    }
}

extern "C" void kernel_launch(void* const* d_in, const int* in_sizes, int n_in,
                              void* d_out, int out_size, void* d_ws, size_t ws_size,
                              hipStream_t stream) {
    const int*   premise    = (const int*)d_in[0];
    const int*   hypothesis = (const int*)d_in[1];
    const float* emb        = (const float*)d_in[2];
    const float* W_ih       = (const float*)d_in[3];
    const float* b_ih       = (const float*)d_in[4];
    const float* W_hh       = (const float*)d_in[5];
    const float* b_hh       = (const float*)d_in[6];
    const float* W_ch       = (const float*)d_in[7];
    const float* b_ch       = (const float*)d_in[8];
    const float* W_cc       = (const float*)d_in[9];
    const float* b_cc       = (const float*)d_in[10];
    const float* W1         = (const float*)d_in[11];
    const float* b1         = (const float*)d_in[12];
    const float* W2         = (const float*)d_in[13];
    const float* b2         = (const float*)d_in[14];
    const float* W3         = (const float*)d_in[15];
    const float* b3         = (const float*)d_in[16];
    float* out = (float*)d_out;
    float* ws  = (float*)d_ws;

    (void)in_sizes; (void)n_in; (void)out_size; (void)ws_size;

    grid_lstm_kernel<<<dim3(256), dim3(256), 0, stream>>>(
        premise, hypothesis, emb, W_ih, b_ih, W_hh, b_hh,
        W_ch, b_ch, W_cc, b_cc, W1, b1, W2, b2, W3, b3, out, ws);
}

// Round 4
// 3651.151 us; speedup vs baseline: 1.5186x; 1.5186x over previous
//
#include <hip/hip_runtime.h>
#include <math.h>

// GridLSTM wavefront-dataflow kernel. V=50000, E=300, H=128, L=32, B=8.
// 256 blocks x 256 threads, plain launch. bid = c*32 + i:
//   i = bid & 31  : grid row this block group owns (walks columns j=0..31)
//   c = bid >> 5  : chunk 0..7 (128 of 1024 gate rows in A; 32 of 256 condense rows in B)
// NO global barriers. Sync primitives (all in ws, poisoned 0xAAAAAAAA each launch):
//   - per-row 8-block monotonic counter barrier (row blocks share an XCD under %8 round-robin)
//   - per-cell ready flags flag[i][j] = MAGIC (point-to-point row i-1 -> row i)
//   - per-row phase-0 flags flag_p[i] (Hypproj[i] ready)
// Fence pattern (proven in round 3 at absmax 0.0): writer __threadfence before
// counter/flag; reader spins, then __threadfence (invalidates CU L1) + __syncthreads.

// ---------------- workspace layout (float words) ----------------
#define P_OFF     0            // Pproj [32][8][1024] (b_ih+b_hh folded in)
#define HYP_OFF   262144       // Hypproj [32][8][1024]
#define GATES_OFF 524288       // Gates [32 rows][8][1024]
#define HN_OFF    786432       // Hn [2 parity][32 j][8][128]
#define CN_OFF    851968       // Cn [2 parity][32 j][8][128]
#define CTR_OFF   917504       // row barrier counters, word stride 32 (128B apart)
#define FLAG_OFF  918528       // cell flags [32][32], then flag_p[32]

#define BAR_BASE 0xAAAAAAAAu
#define MAGIC    0x1F2E3D4Cu

__device__ __forceinline__ float sigm(float x) { return 1.f / (1.f + __expf(-x)); }
__device__ __forceinline__ float tanh_fast(float x) { return 1.f - 2.f / (__expf(2.f * x) + 1.f); }

// 8-participant row barrier, monotonic counter (base = poison 0xAAAAAAAA).
__device__ __forceinline__ void row_barrier(unsigned* ctr, unsigned k) {
    __threadfence();
    __syncthreads();
    if (threadIdx.x == 0) {
        atomicAdd(ctr, 1u);
        const unsigned target = k * 8u;
        long spins = 0;
        while ((__hip_atomic_load(ctr, __ATOMIC_RELAXED, __HIP_MEMORY_SCOPE_AGENT)
                - BAR_BASE) < target) {
            __builtin_amdgcn_s_sleep(1);
            if (++spins > (1L << 26)) break;   // failsafe: wrong answer > hang
        }
        __threadfence();
    }
    __syncthreads();
}

__device__ __forceinline__ void wait_flag(unsigned* f) {
    long spins = 0;
    while (__hip_atomic_load(f, __ATOMIC_RELAXED, __HIP_MEMORY_SCOPE_AGENT) != MAGIC) {
        __builtin_amdgcn_s_sleep(1);
        if (++spins > (1L << 26)) break;
    }
}

__global__ void __launch_bounds__(256, 1) grid_lstm_kernel(
    const int* __restrict__ premise, const int* __restrict__ hypothesis,
    const float* __restrict__ emb,
    const float* __restrict__ W_ih, const float* __restrict__ b_ih,
    const float* __restrict__ W_hh, const float* __restrict__ b_hh,
    const float* __restrict__ W_ch, const float* __restrict__ b_ch,
    const float* __restrict__ W_cc, const float* __restrict__ b_cc,
    const float* __restrict__ W1, const float* __restrict__ b1,
    const float* __restrict__ W2, const float* __restrict__ b2,
    const float* __restrict__ W3, const float* __restrict__ b3,
    float* __restrict__ out, float* __restrict__ ws)
{
    __shared__ float hin[8 * 256];     // h_in staging [8][256] (b-major)
    __shared__ float red[256 * 33];    // GEMM partials / phase0 emb / phaseB h,c / MLP

    const int tid = threadIdx.x;
    const int bid = blockIdx.x;
    const int i   = bid & 31;          // grid row
    const int c   = bid >> 5;          // chunk

    float* Pproj   = ws + P_OFF;
    float* Hypproj = ws + HYP_OFF;
    float* GatesR  = ws + GATES_OFF + i * 8192;       // this row's gates [8][1024]
    float* Hn      = ws + HN_OFF;                     // [2][32][8][128]
    float* Cn      = ws + CN_OFF;
    unsigned* ctr   = (unsigned*)(ws + CTR_OFF) + i * 32;
    unsigned* flags = (unsigned*)(ws + FLAG_OFF);     // [32][32] cell flags
    unsigned* flagp = flags + 1024;                   // [32] phase-0 flags
    unsigned rk = 0;

    // ================= Phase 0: Pproj[i] and Hypproj[i] =================
    {
        float* embs = red;   // [2 sides][8][300]
        for (int idx = tid; idx < 4800; idx += 256) {
            int side = idx / 2400, rem = idx - side * 2400;
            int b = rem / 300, e = rem - b * 300;
            const int* toks = side ? hypothesis : premise;
            embs[idx] = emb[(long)toks[b * 32 + i] * 300 + e];
        }
        __syncthreads();
        #pragma unroll 1
        for (int q = 0; q < 4; q++) {
            const int oo = tid + q * 256;
            const int b = oo >> 7, g = oo & 127;
            const int gr = c * 128 + g;
            float accP = b_ih[gr] + b_hh[gr];
            float accH = 0.f;
            const float* wp = W_ih + (long)gr * 600;       // premise cols [0,300)
            const float* eP = embs + b * 300;
            const float* eH = embs + 2400 + b * 300;
            for (int e = 0; e < 300; e += 4) {
                float4 w1 = *(const float4*)(wp + e);
                float4 w2 = *(const float4*)(wp + 300 + e);
                float4 p4 = *(const float4*)(eP + e);
                float4 h4 = *(const float4*)(eH + e);
                accP += w1.x * p4.x + w1.y * p4.y + w1.z * p4.z + w1.w * p4.w;
                accH += w2.x * h4.x + w2.y * h4.y + w2.z * h4.z + w2.w * h4.w;
            }
            Pproj[i * 8192 + b * 1024 + gr]   = accP;
            Hypproj[i * 8192 + b * 1024 + gr] = accH;
        }
    }
    row_barrier(ctr, ++rk);
    if (c == 0 && tid == 0)
        __hip_atomic_store(&flagp[i], MAGIC, __ATOMIC_RELEASE, __HIP_MEMORY_SCOPE_AGENT);

    // ---- W_hh chunk -> registers. Thread (gg=tid&31, ks=tid>>5) holds gate rows
    // c*128 + gg*4 + a (a=0..3), K-seg k in [ks*32, ks*32+32).
    const int gg = tid & 31, ks = tid >> 5;
    float4 w[4][8];
    #pragma unroll
    for (int a = 0; a < 4; a++) {
        const float* wrow = W_hh + (c * 128 + gg * 4 + a) * 256 + ks * 32;
        #pragma unroll
        for (int cc = 0; cc < 8; cc++) w[a][cc] = *(const float4*)(wrow + cc * 4);
    }

    // ================= Wavefront: this row walks j = 0..31 =================
    #pragma unroll 1
    for (int j = 0; j < 31 + 1; j++) {
        const int pcur = i & 1, pup = (i - 1) & 1;

        // ---- wait for dependencies (up-cell flag, Hypproj[j] flag) ----
        if (tid == 0) {
            if (i > 0) wait_flag(&flags[(i - 1) * 32 + j]);
            wait_flag(&flagp[j]);
            __threadfence();            // L1 invalidate for the whole CU
        }
        __syncthreads();

        // ---- Phase A: gates GEMM ----
        // stage h_in = [h_up(128) ; h_left(128)] for 8 batches
        #pragma unroll
        for (int rep = 0; rep < 8; rep++) {
            int idx = rep * 256 + tid;
            int b = idx >> 8, k = idx & 255;
            float v = 0.f;
            if (k < 128) { if (i > 0) v = Hn[(pup * 32 + j) * 1024 + b * 128 + k]; }
            else         { if (j > 0) v = Hn[(pcur * 32 + j - 1) * 1024 + b * 128 + (k - 128)]; }
            hin[idx] = v;
        }
        __syncthreads();
        {
            const float* hb = hin + ks * 32;
            float acc[4][8];
            #pragma unroll
            for (int a = 0; a < 4; a++)
                #pragma unroll
                for (int b = 0; b < 8; b++) acc[a][b] = 0.f;
            #pragma unroll
            for (int cc = 0; cc < 8; cc++) {
                #pragma unroll
                for (int b = 0; b < 8; b++) {
                    float4 h = *(const float4*)(hb + b * 256 + cc * 4);
                    #pragma unroll
                    for (int a = 0; a < 4; a++)
                        acc[a][b] += w[a][cc].x * h.x + w[a][cc].y * h.y
                                   + w[a][cc].z * h.z + w[a][cc].w * h.w;
                }
            }
            // partials -> LDS, then 256-thread parallel reduction (4 outputs each)
            #pragma unroll
            for (int a = 0; a < 4; a++)
                #pragma unroll
                for (int b = 0; b < 8; b++)
                    red[tid * 33 + a * 8 + b] = acc[a][b];
        }
        __syncthreads();
        #pragma unroll
        for (int q = 0; q < 4; q++) {
            const int oo = tid + q * 256;
            const int b = oo >> 7, g = oo & 127;
            const int gg2 = g >> 2, a2 = g & 3;
            float s = 0.f;
            #pragma unroll
            for (int k2 = 0; k2 < 8; k2++)
                s += red[(k2 * 32 + gg2) * 33 + a2 * 8 + b];
            s += Pproj[i * 8192 + b * 1024 + c * 128 + g]
               + Hypproj[j * 8192 + b * 1024 + c * 128 + g];
            GatesR[b * 1024 + c * 128 + g] = s;
        }
        row_barrier(ctr, ++rk);

        // ---- Phase B: elementwise + condense ----
        float* stc = red;           // c_new [8][256]
        float* sth = red + 2048;    // h_new [8][256]
        #pragma unroll
        for (int rep = 0; rep < 8; rep++) {
            int idx = rep * 256 + tid;
            int b = idx >> 8, t = idx & 255;
            float gi = GatesR[b * 1024 + t];
            float gf = GatesR[b * 1024 + 256 + t];
            float gc = GatesR[b * 1024 + 512 + t];
            float go = GatesR[b * 1024 + 768 + t];
            float cin = 0.f;
            if (t < 128) { if (i > 0) cin = Cn[(pup * 32 + j) * 1024 + b * 128 + t]; }
            else         { if (j > 0) cin = Cn[(pcur * 32 + j - 1) * 1024 + b * 128 + (t - 128)]; }
            float cn = sigm(gf) * cin + sigm(gi) * tanh_fast(gc);
            float hn = sigm(go) * tanh_fast(cn);
            stc[idx] = cn;
            sth[idx] = hn;
        }
        __syncthreads();
        {
            const int r = tid & 31, b = tid >> 5;
            const int row = c * 16 + (r & 15);
            const float* src; const float* Wm; float bias; float* dst;
            if (r < 16) { src = sth; Wm = W_ch; bias = b_ch[row];
                          dst = Hn + (pcur * 32 + j) * 1024 + b * 128 + row; }
            else        { src = stc; Wm = W_cc; bias = b_cc[row];
                          dst = Cn + (pcur * 32 + j) * 1024 + b * 128 + row; }
            const float* wrow = Wm + row * 256;
            const float* x = src + b * 256;
            float a2 = bias;
            for (int k = 0; k < 256; k += 4) {
                float4 wv = *(const float4*)(wrow + k);
                float4 xv = *(const float4*)(x + k);
                a2 += wv.x * xv.x + wv.y * xv.y + wv.z * xv.z + wv.w * xv.w;
            }
            *dst = a2;
        }
        row_barrier(ctr, ++rk);
        if (c == 0 && tid == 0)
            __hip_atomic_store(&flags[i * 32 + j], MAGIC,
                               __ATOMIC_RELEASE, __HIP_MEMORY_SCOPE_AGENT);
    }

    // ================= Final MLP + softmax (block of row 31, chunk 0) =================
    if (bid == 31) {
        const float* hsrc = Hn + ((31 & 1) * 32 + 31) * 1024;   // [8][128]
        float* s1 = red;
        float* s2 = red + 1024;
        for (int idx = tid; idx < 1024; idx += 256) s1[idx] = hsrc[idx];
        __syncthreads();
        for (int idx = tid; idx < 1024; idx += 256) {
            int b = idx >> 7, o = idx & 127;
            float a = b1[o];
            const float* wr = W1 + o * 128; const float* x = s1 + b * 128;
            for (int k = 0; k < 128; k++) a += wr[k] * x[k];
            s2[idx] = fmaxf(a, 0.f);
        }
        __syncthreads();
        for (int idx = tid; idx < 1024; idx += 256) {
            int b = idx >> 7, o = idx & 127;
            float a = b2[o];
            const float* wr = W2 + o * 128; const float* x = s2 + b * 128;
            for (int k = 0; k < 128; k++) a += wr[k] * x[k];
            s1[idx] = fmaxf(a, 0.f);
        }
        __syncthreads();
        if (tid < 8) {
            const int b = tid;
            float lg[3];
            for (int cc = 0; cc < 3; cc++) {
                float a = b3[cc];
                const float* wr = W3 + cc * 128; const float* x = s1 + b * 128;
                for (int k = 0; k < 128; k++) a += wr[k] * x[k];
                lg[cc] = a;
            }
            float m = fmaxf(lg[0], fmaxf(lg[1], lg[2]));
            float e0 = expf(lg[0] - m), e1 = expf(lg[1] - m), e2 = expf(lg[2] - m);
            float s = e0 + e1 + e2;
            out[b * 3 + 0] = e0 / s;
            out[b * 3 + 1] = e1 / s;
            out[b * 3 + 2] = e2 / s;
        }
    }
}

extern "C" void kernel_launch(void* const* d_in, const int* in_sizes, int n_in,
                              void* d_out, int out_size, void* d_ws, size_t ws_size,
                              hipStream_t stream) {
    const int*   premise    = (const int*)d_in[0];
    const int*   hypothesis = (const int*)d_in[1];
    const float* emb        = (const float*)d_in[2];
    const float* W_ih       = (const float*)d_in[3];
    const float* b_ih       = (const float*)d_in[4];
    const float* W_hh       = (const float*)d_in[5];
    const float* b_hh       = (const float*)d_in[6];
    const float* W_ch       = (const float*)d_in[7];
    const float* b_ch       = (const float*)d_in[8];
    const float* W_cc       = (const float*)d_in[9];
    const float* b_cc       = (const float*)d_in[10];
    const float* W1         = (const float*)d_in[11];
    const float* b1         = (const float*)d_in[12];
    const float* W2         = (const float*)d_in[13];
    const float* b2         = (const float*)d_in[14];
    const float* W3         = (const float*)d_in[15];
    const float* b3         = (const float*)d_in[16];
    float* out = (float*)d_out;
    float* ws  = (float*)d_ws;

    (void)in_sizes; (void)n_in; (void)out_size; (void)ws_size;

    grid_lstm_kernel<<<dim3(256), dim3(256), 0, stream>>>(
        premise, hypothesis, emb, W_ih, b_ih, W_hh, b_hh,
        W_ch, b_ch, W_cc, b_cc, W1, b1, W2, b2, W3, b3, out, ws);
}

// Round 5
// 1859.081 us; speedup vs baseline: 2.9825x; 1.9640x over previous
//
#include <hip/hip_runtime.h>
#include <math.h>

// GridLSTM fence-free dataflow kernel. V=50000, E=300, H=128, L=32, B=8.
// 256 blocks x 256 threads, plain launch. bid = c*32 + i (i=row, c=chunk 0..7).
// NO barriers, NO __threadfence. All cross-block data moves via relaxed
// agent-scope atomics (sc1: L1/L2-bypass, coherence-point). Producer order:
// data atomics -> s_waitcnt vmcnt(0) -> __syncthreads -> release-store flag.
// Consumers spin on flags with relaxed atomic loads (8 flags in parallel).
// Flags are monotonic: value = 0xAAAAAAAA (ws poison) + (j+1).

// ---------------- workspace layout (float words) ----------------
#define P_OFF     0            // Pproj [32][8][1024] (b_ih+b_hh folded in)  own-block only
#define HYP_OFF   262144       // Hypproj [32][8][1024]        cross-block (atomic)
#define GATES_OFF 524288       // Gates [32 row][2 par][8 b][1024]  cross-block (atomic)
#define HN_OFF    1048576      // Hn [4 dep][32 j][8][128]     cross-block (atomic)
#define CN_OFF    1179648      // Cn [4 dep][32 j][8][128]     cross-block (atomic)
#define FLAGS_OFF 1310720      // HypF[32][8] | GateF[32][8] | HF[32][8], 32-word stride

#define BASE 0xAAAAAAAAu

__device__ __forceinline__ float sigm(float x) { return 1.f / (1.f + __expf(-x)); }
__device__ __forceinline__ float tanh_fast(float x) { return 1.f - 2.f / (__expf(2.f * x) + 1.f); }

__device__ __forceinline__ unsigned ld_flag(const unsigned* p) {
    return __hip_atomic_load(p, __ATOMIC_RELAXED, __HIP_MEMORY_SCOPE_AGENT);
}
__device__ __forceinline__ void st_flag_rel(unsigned* p, unsigned v) {
    __hip_atomic_store(p, v, __ATOMIC_RELEASE, __HIP_MEMORY_SCOPE_AGENT);
}
__device__ __forceinline__ float ld_f32(const float* p) {
    unsigned u = __hip_atomic_load((const unsigned*)p, __ATOMIC_RELAXED, __HIP_MEMORY_SCOPE_AGENT);
    return __uint_as_float(u);
}
__device__ __forceinline__ void st_f32(float* p, float v) {
    __hip_atomic_store((unsigned*)p, __float_as_uint(v), __ATOMIC_RELAXED, __HIP_MEMORY_SCOPE_AGENT);
}
__device__ __forceinline__ float2 ld_f32x2(const float* p) {   // p 8B-aligned
    unsigned long long u = __hip_atomic_load((const unsigned long long*)p,
                                             __ATOMIC_RELAXED, __HIP_MEMORY_SCOPE_AGENT);
    float2 r; r.x = __uint_as_float((unsigned)u); r.y = __uint_as_float((unsigned)(u >> 32));
    return r;
}
__device__ __forceinline__ void wait_ge(const unsigned* f, unsigned target) {
    long spins = 0;
    while ((ld_flag(f) - BASE) < target) {
        __builtin_amdgcn_s_sleep(1);
        if (++spins > (1L << 22)) break;   // failsafe: wrong answer > hang
    }
}
__device__ __forceinline__ void drain_vmem() {
    asm volatile("s_waitcnt vmcnt(0)" ::: "memory");
}

__global__ void __launch_bounds__(256, 1) grid_lstm_kernel(
    const int* __restrict__ premise, const int* __restrict__ hypothesis,
    const float* __restrict__ emb,
    const float* __restrict__ W_ih, const float* __restrict__ b_ih,
    const float* __restrict__ W_hh, const float* __restrict__ b_hh,
    const float* __restrict__ W_ch, const float* __restrict__ b_ch,
    const float* __restrict__ W_cc, const float* __restrict__ b_cc,
    const float* __restrict__ W1, const float* __restrict__ b1,
    const float* __restrict__ W2, const float* __restrict__ b2,
    const float* __restrict__ W3, const float* __restrict__ b3,
    float* __restrict__ out, float* __restrict__ ws)
{
    __shared__ float hin[8 * 256];     // h_in staging [8][256] (b-major)
    __shared__ float red[256 * 33];    // GEMM partials / phase0 emb / phaseB h,c / MLP

    const int tid = threadIdx.x;
    const int bid = blockIdx.x;
    const int i   = bid & 31;          // grid row
    const int c   = bid >> 5;          // chunk

    float* Pproj   = ws + P_OFF;
    float* Hypproj = ws + HYP_OFF;
    float* Gates   = ws + GATES_OFF;
    float* Hn      = ws + HN_OFF;      // [(dep)*32 + j][8][128]
    float* Cn      = ws + CN_OFF;
    unsigned* flags = (unsigned*)(ws + FLAGS_OFF);
    unsigned* HypF  = flags;                  // (j*8+c)*32
    unsigned* GateF = flags + 8192;           // (i*8+c)*32
    unsigned* HF    = flags + 16384;          // (i*8+c)*32

    // ================= Phase 0: Pproj[i] and Hypproj[i] =================
    {
        float* embs = red;   // [2 sides][8][300]
        for (int idx = tid; idx < 4800; idx += 256) {
            int side = idx / 2400, rem = idx - side * 2400;
            int b = rem / 300, e = rem - b * 300;
            const int* toks = side ? hypothesis : premise;
            embs[idx] = emb[(long)toks[b * 32 + i] * 300 + e];
        }
        __syncthreads();
        #pragma unroll 1
        for (int q = 0; q < 4; q++) {
            const int oo = tid + q * 256;
            const int b = oo >> 7, g = oo & 127;
            const int gr = c * 128 + g;
            float accP = b_ih[gr] + b_hh[gr];
            float accH = 0.f;
            const float* wp = W_ih + (long)gr * 600;
            const float* eP = embs + b * 300;
            const float* eH = embs + 2400 + b * 300;
            for (int e = 0; e < 300; e += 4) {
                float4 w1 = *(const float4*)(wp + e);
                float4 w2 = *(const float4*)(wp + 300 + e);
                float4 p4 = *(const float4*)(eP + e);
                float4 h4 = *(const float4*)(eH + e);
                accP += w1.x * p4.x + w1.y * p4.y + w1.z * p4.z + w1.w * p4.w;
                accH += w2.x * h4.x + w2.y * h4.y + w2.z * h4.z + w2.w * h4.w;
            }
            Pproj[i * 8192 + b * 1024 + gr] = accP;                 // own-block
            st_f32(&Hypproj[i * 8192 + b * 1024 + gr], accH);       // cross-block
        }
    }
    drain_vmem();
    __syncthreads();
    if (tid == 0) st_flag_rel(&HypF[(i * 8 + c) * 32], BASE + 1u);

    // ---- W_hh chunk -> registers (thread gg=tid&31, ks=tid>>5; rows c*128+gg*4+a).
    const int gg = tid & 31, ks = tid >> 5;
    float4 w[4][8];
    #pragma unroll
    for (int a = 0; a < 4; a++) {
        const float* wrow = W_hh + (c * 128 + gg * 4 + a) * 256 + ks * 32;
        #pragma unroll
        for (int cc = 0; cc < 8; cc++) w[a][cc] = *(const float4*)(wrow + cc * 4);
    }

    // ================= Wavefront: this row walks j = 0..31 =================
    #pragma unroll 1
    for (int j = 0; j < 32; j++) {
        // ---- top-of-cell waits (parallel spinners) ----
        if (i > 0 && tid < 8)               wait_ge(&HF[((i - 1) * 8 + tid) * 32], (unsigned)(j + 1));
        if (j > 0 && tid >= 8 && tid < 16)  wait_ge(&HF[(i * 8 + (tid - 8)) * 32], (unsigned)j);
        if (tid >= 16 && tid < 24)          wait_ge(&HypF[(j * 8 + (tid - 16)) * 32], 1u);
        __syncthreads();

        // ---- Phase A: stage h_in = [h_up(128) ; h_left(128)] (atomic pair loads) ----
        #pragma unroll
        for (int rep = 0; rep < 4; rep++) {
            int idx = rep * 256 + tid;              // 0..1023
            int b = idx >> 7, kk = (idx & 127) * 2; // kk even, [0,256)
            float2 v = make_float2(0.f, 0.f);
            if (kk < 128) {
                if (i > 0) v = ld_f32x2(&Hn[((((i - 1) & 3) * 32 + j) * 1024) + b * 128 + kk]);
            } else {
                if (j > 0) v = ld_f32x2(&Hn[(((i & 3) * 32 + (j - 1)) * 1024) + b * 128 + (kk - 128)]);
            }
            hin[b * 256 + kk]     = v.x;
            hin[b * 256 + kk + 1] = v.y;
        }
        __syncthreads();
        {
            const float* hb = hin + ks * 32;
            float acc[4][8];
            #pragma unroll
            for (int a = 0; a < 4; a++)
                #pragma unroll
                for (int b = 0; b < 8; b++) acc[a][b] = 0.f;
            #pragma unroll
            for (int cc = 0; cc < 8; cc++) {
                #pragma unroll
                for (int b = 0; b < 8; b++) {
                    float4 h = *(const float4*)(hb + b * 256 + cc * 4);
                    #pragma unroll
                    for (int a = 0; a < 4; a++)
                        acc[a][b] += w[a][cc].x * h.x + w[a][cc].y * h.y
                                   + w[a][cc].z * h.z + w[a][cc].w * h.w;
                }
            }
            #pragma unroll
            for (int a = 0; a < 4; a++)
                #pragma unroll
                for (int b = 0; b < 8; b++)
                    red[tid * 33 + a * 8 + b] = acc[a][b];
        }
        __syncthreads();
        float* GRow = Gates + i * 16384 + (j & 1) * 8192;
        #pragma unroll
        for (int q = 0; q < 4; q++) {
            const int oo = tid + q * 256;
            const int b = oo >> 7, g = oo & 127;
            const int gg2 = g >> 2, a2 = g & 3;
            float s = 0.f;
            #pragma unroll
            for (int k2 = 0; k2 < 8; k2++)
                s += red[(k2 * 32 + gg2) * 33 + a2 * 8 + b];
            s += Pproj[i * 8192 + b * 1024 + c * 128 + g]
               + ld_f32(&Hypproj[j * 8192 + b * 1024 + c * 128 + g]);
            st_f32(&GRow[b * 1024 + c * 128 + g], s);
        }
        drain_vmem();
        __syncthreads();
        if (tid == 0) st_flag_rel(&GateF[(i * 8 + c) * 32], BASE + (unsigned)(j + 1));

        // ---- wait all gate chunks of this row ----
        if (tid < 8) wait_ge(&GateF[(i * 8 + tid) * 32], (unsigned)(j + 1));
        __syncthreads();

        // ---- Phase B: elementwise (pair loads) + condense ----
        float* stc = red;           // c_new [8][256]
        float* sth = red + 2048;    // h_new [8][256]
        #pragma unroll
        for (int rep = 0; rep < 4; rep++) {
            int idx = rep * 256 + tid;              // 0..1023
            int b = idx >> 7, tp = (idx & 127) * 2; // even t, [0,256)
            const float* Gb = GRow + b * 1024;
            float2 gi = ld_f32x2(Gb + tp);
            float2 gf = ld_f32x2(Gb + 256 + tp);
            float2 gc = ld_f32x2(Gb + 512 + tp);
            float2 go = ld_f32x2(Gb + 768 + tp);
            float2 cin = make_float2(0.f, 0.f);
            if (tp < 128) {
                if (i > 0) cin = ld_f32x2(&Cn[((((i - 1) & 3) * 32 + j) * 1024) + b * 128 + tp]);
            } else {
                if (j > 0) cin = ld_f32x2(&Cn[(((i & 3) * 32 + (j - 1)) * 1024) + b * 128 + (tp - 128)]);
            }
            float cn0 = sigm(gf.x) * cin.x + sigm(gi.x) * tanh_fast(gc.x);
            float cn1 = sigm(gf.y) * cin.y + sigm(gi.y) * tanh_fast(gc.y);
            float hn0 = sigm(go.x) * tanh_fast(cn0);
            float hn1 = sigm(go.y) * tanh_fast(cn1);
            stc[b * 256 + tp] = cn0; stc[b * 256 + tp + 1] = cn1;
            sth[b * 256 + tp] = hn0; sth[b * 256 + tp + 1] = hn1;
        }
        __syncthreads();
        {
            const int r = tid & 31, b = tid >> 5;
            const int row = c * 16 + (r & 15);
            const float* src; const float* Wm; float bias; float* dst;
            if (r < 16) { src = sth; Wm = W_ch; bias = b_ch[row];
                          dst = &Hn[(((i & 3) * 32 + j) * 1024) + b * 128 + row]; }
            else        { src = stc; Wm = W_cc; bias = b_cc[row];
                          dst = &Cn[(((i & 3) * 32 + j) * 1024) + b * 128 + row]; }
            const float* wrow = Wm + row * 256;
            const float* x = src + b * 256;
            float a2 = bias;
            for (int k = 0; k < 256; k += 4) {
                float4 wv = *(const float4*)(wrow + k);
                float4 xv = *(const float4*)(x + k);
                a2 += wv.x * xv.x + wv.y * xv.y + wv.z * xv.z + wv.w * xv.w;
            }
            st_f32(dst, a2);
        }
        drain_vmem();
        __syncthreads();
        if (tid == 0) st_flag_rel(&HF[(i * 8 + c) * 32], BASE + (unsigned)(j + 1));
    }

    // ================= Final MLP + softmax (block i=31, c=0) =================
    if (bid == 31) {
        if (tid < 8) wait_ge(&HF[(31 * 8 + tid) * 32], 32u);
        __syncthreads();
        float* s1 = red;
        float* s2 = red + 1024;
        for (int idx = tid; idx < 1024; idx += 256)
            s1[idx] = ld_f32(&Hn[(((31 & 3) * 32 + 31) * 1024) + idx]);
        __syncthreads();
        for (int idx = tid; idx < 1024; idx += 256) {
            int b = idx >> 7, o = idx & 127;
            float a = b1[o];
            const float* wr = W1 + o * 128; const float* x = s1 + b * 128;
            for (int k = 0; k < 128; k++) a += wr[k] * x[k];
            s2[idx] = fmaxf(a, 0.f);
        }
        __syncthreads();
        for (int idx = tid; idx < 1024; idx += 256) {
            int b = idx >> 7, o = idx & 127;
            float a = b2[o];
            const float* wr = W2 + o * 128; const float* x = s2 + b * 128;
            for (int k = 0; k < 128; k++) a += wr[k] * x[k];
            s1[idx] = fmaxf(a, 0.f);
        }
        __syncthreads();
        if (tid < 8) {
            const int b = tid;
            float lg[3];
            for (int cc = 0; cc < 3; cc++) {
                float a = b3[cc];
                const float* wr = W3 + cc * 128; const float* x = s1 + b * 128;
                for (int k = 0; k < 128; k++) a += wr[k] * x[k];
                lg[cc] = a;
            }
            float m = fmaxf(lg[0], fmaxf(lg[1], lg[2]));
            float e0 = expf(lg[0] - m), e1 = expf(lg[1] - m), e2 = expf(lg[2] - m);
            float s = e0 + e1 + e2;
            out[b * 3 + 0] = e0 / s;
            out[b * 3 + 1] = e1 / s;
            out[b * 3 + 2] = e2 / s;
        }
    }
}

extern "C" void kernel_launch(void* const* d_in, const int* in_sizes, int n_in,
                              void* d_out, int out_size, void* d_ws, size_t ws_size,
                              hipStream_t stream) {
    const int*   premise    = (const int*)d_in[0];
    const int*   hypothesis = (const int*)d_in[1];
    const float* emb        = (const float*)d_in[2];
    const float* W_ih       = (const float*)d_in[3];
    const float* b_ih       = (const float*)d_in[4];
    const float* W_hh       = (const float*)d_in[5];
    const float* b_hh       = (const float*)d_in[6];
    const float* W_ch       = (const float*)d_in[7];
    const float* b_ch       = (const float*)d_in[8];
    const float* W_cc       = (const float*)d_in[9];
    const float* b_cc       = (const float*)d_in[10];
    const float* W1         = (const float*)d_in[11];
    const float* b1         = (const float*)d_in[12];
    const float* W2         = (const float*)d_in[13];
    const float* b2         = (const float*)d_in[14];
    const float* W3         = (const float*)d_in[15];
    const float* b3         = (const float*)d_in[16];
    float* out = (float*)d_out;
    float* ws  = (float*)d_ws;

    (void)in_sizes; (void)n_in; (void)out_size; (void)ws_size;

    grid_lstm_kernel<<<dim3(256), dim3(256), 0, stream>>>(
        premise, hypothesis, emb, W_ih, b_ih, W_hh, b_hh,
        W_ch, b_ch, W_cc, b_cc, W1, b1, W2, b2, W3, b3, out, ws);
}

// Round 6
// 1693.683 us; speedup vs baseline: 3.2738x; 1.0977x over previous
//
#include <hip/hip_runtime.h>
#include <math.h>

// GridLSTM fence-free dataflow kernel. V=50000, E=300, H=128, L=32, B=8.
// 256 blocks x 256 threads, plain launch. bid = c*32 + i (i=row, c=chunk 0..7).
// NO barriers, NO __threadfence, NO release stores (agent-release emits an L2
// writeback on gfx950 — ~10us). Protocol: cross-block data via relaxed
// agent-scope atomics (sc-bypass, acked at coherence point); producer does
// data stores -> s_waitcnt vmcnt(0) -> __syncthreads -> RELAXED flag store.
// Data is globally visible before the flag can be observed. Consumers spin on
// flags with relaxed loads. Flags monotonic: value = 0xAAAAAAAA + (j+1).

// ---------------- workspace layout (float words) ----------------
#define P_OFF     0            // Pproj [32][8][1024] (b_ih+b_hh folded in)  own-block only
#define HYP_OFF   262144       // Hypproj [32][8][1024]        cross-block (atomic)
#define GATES_OFF 524288       // Gates [32 row][2 par][8 b][1024]  cross-block (atomic)
#define HN_OFF    1048576      // Hn [4 dep][32 j][8][128]     cross-block (atomic)
#define CN_OFF    1179648      // Cn [4 dep][32 j][8][128]     cross-block (atomic)
#define FLAGS_OFF 1310720      // HypF[32][8] | GateF[32][8] | HF[32][8], 32-word stride

#define BASE 0xAAAAAAAAu

__device__ __forceinline__ float sigm(float x) { return 1.f / (1.f + __expf(-x)); }
__device__ __forceinline__ float tanh_fast(float x) { return 1.f - 2.f / (__expf(2.f * x) + 1.f); }

__device__ __forceinline__ unsigned ld_flag(const unsigned* p) {
    return __hip_atomic_load(p, __ATOMIC_RELAXED, __HIP_MEMORY_SCOPE_AGENT);
}
__device__ __forceinline__ void st_flag_relaxed(unsigned* p, unsigned v) {
    __hip_atomic_store(p, v, __ATOMIC_RELAXED, __HIP_MEMORY_SCOPE_AGENT);
}
__device__ __forceinline__ float ld_f32(const float* p) {
    unsigned u = __hip_atomic_load((const unsigned*)p, __ATOMIC_RELAXED, __HIP_MEMORY_SCOPE_AGENT);
    return __uint_as_float(u);
}
__device__ __forceinline__ void st_f32(float* p, float v) {
    __hip_atomic_store((unsigned*)p, __float_as_uint(v), __ATOMIC_RELAXED, __HIP_MEMORY_SCOPE_AGENT);
}
__device__ __forceinline__ float2 ld_f32x2(const float* p) {   // p 8B-aligned
    unsigned long long u = __hip_atomic_load((const unsigned long long*)p,
                                             __ATOMIC_RELAXED, __HIP_MEMORY_SCOPE_AGENT);
    float2 r; r.x = __uint_as_float((unsigned)u); r.y = __uint_as_float((unsigned)(u >> 32));
    return r;
}
__device__ __forceinline__ void wait_ge(const unsigned* f, unsigned target) {
    long spins = 0;
    while ((ld_flag(f) - BASE) < target) {
        __builtin_amdgcn_s_sleep(1);
        if (++spins > (1L << 22)) break;   // failsafe: wrong answer > hang
    }
}
__device__ __forceinline__ void drain_vmem() {
    asm volatile("s_waitcnt vmcnt(0)" ::: "memory");
}

__global__ void __launch_bounds__(256, 1) grid_lstm_kernel(
    const int* __restrict__ premise, const int* __restrict__ hypothesis,
    const float* __restrict__ emb,
    const float* __restrict__ W_ih, const float* __restrict__ b_ih,
    const float* __restrict__ W_hh, const float* __restrict__ b_hh,
    const float* __restrict__ W_ch, const float* __restrict__ b_ch,
    const float* __restrict__ W_cc, const float* __restrict__ b_cc,
    const float* __restrict__ W1, const float* __restrict__ b1,
    const float* __restrict__ W2, const float* __restrict__ b2,
    const float* __restrict__ W3, const float* __restrict__ b3,
    float* __restrict__ out, float* __restrict__ ws)
{
    __shared__ float hin[8 * 256];     // h_in staging [8][256] (b-major)
    __shared__ float red[256 * 33];    // GEMM partials / phase0 emb / phaseB h,c / MLP

    const int tid = threadIdx.x;
    const int bid = blockIdx.x;
    const int i   = bid & 31;          // grid row
    const int c   = bid >> 5;          // chunk

    float* Pproj   = ws + P_OFF;
    float* Hypproj = ws + HYP_OFF;
    float* Gates   = ws + GATES_OFF;
    float* Hn      = ws + HN_OFF;      // [(dep)*32 + j][8][128]
    float* Cn      = ws + CN_OFF;
    unsigned* flags = (unsigned*)(ws + FLAGS_OFF);
    unsigned* HypF  = flags;                  // (j*8+c)*32
    unsigned* GateF = flags + 8192;           // (i*8+c)*32
    unsigned* HF    = flags + 16384;          // (i*8+c)*32

    // ================= Phase 0: Pproj[i] and Hypproj[i] =================
    {
        float* embs = red;   // [2 sides][8][300]
        for (int idx = tid; idx < 4800; idx += 256) {
            int side = idx / 2400, rem = idx - side * 2400;
            int b = rem / 300, e = rem - b * 300;
            const int* toks = side ? hypothesis : premise;
            embs[idx] = emb[(long)toks[b * 32 + i] * 300 + e];
        }
        __syncthreads();
        #pragma unroll 1
        for (int q = 0; q < 4; q++) {
            const int oo = tid + q * 256;
            const int b = oo >> 7, g = oo & 127;
            const int gr = c * 128 + g;
            float accP = b_ih[gr] + b_hh[gr];
            float accH = 0.f;
            const float* wp = W_ih + (long)gr * 600;
            const float* eP = embs + b * 300;
            const float* eH = embs + 2400 + b * 300;
            for (int e = 0; e < 300; e += 4) {
                float4 w1 = *(const float4*)(wp + e);
                float4 w2 = *(const float4*)(wp + 300 + e);
                float4 p4 = *(const float4*)(eP + e);
                float4 h4 = *(const float4*)(eH + e);
                accP += w1.x * p4.x + w1.y * p4.y + w1.z * p4.z + w1.w * p4.w;
                accH += w2.x * h4.x + w2.y * h4.y + w2.z * h4.z + w2.w * h4.w;
            }
            Pproj[i * 8192 + b * 1024 + gr] = accP;                 // own-block
            st_f32(&Hypproj[i * 8192 + b * 1024 + gr], accH);       // cross-block
        }
    }
    drain_vmem();
    __syncthreads();
    if (tid == 0) st_flag_relaxed(&HypF[(i * 8 + c) * 32], BASE + 1u);

    // ---- W_hh chunk -> registers (thread gg=tid&31, ks=tid>>5; rows c*128+gg*4+a).
    const int gg = tid & 31, ks = tid >> 5;
    float4 w[4][8];
    #pragma unroll
    for (int a = 0; a < 4; a++) {
        const float* wrow = W_hh + (c * 128 + gg * 4 + a) * 256 + ks * 32;
        #pragma unroll
        for (int cc = 0; cc < 8; cc++) w[a][cc] = *(const float4*)(wrow + cc * 4);
    }

    // ================= Wavefront: this row walks j = 0..31 =================
    #pragma unroll 1
    for (int j = 0; j < 32; j++) {
        // ---- top-of-cell waits (parallel spinners) ----
        if (i > 0 && tid < 8)               wait_ge(&HF[((i - 1) * 8 + tid) * 32], (unsigned)(j + 1));
        if (j > 0 && tid >= 8 && tid < 16)  wait_ge(&HF[(i * 8 + (tid - 8)) * 32], (unsigned)j);
        if (tid >= 16 && tid < 24)          wait_ge(&HypF[(j * 8 + (tid - 16)) * 32], 1u);
        __syncthreads();

        // ---- Phase A: stage h_in = [h_up(128) ; h_left(128)] (atomic pair loads) ----
        #pragma unroll
        for (int rep = 0; rep < 4; rep++) {
            int idx = rep * 256 + tid;              // 0..1023
            int b = idx >> 7, kk = (idx & 127) * 2; // kk even, [0,256)
            float2 v = make_float2(0.f, 0.f);
            if (kk < 128) {
                if (i > 0) v = ld_f32x2(&Hn[((((i - 1) & 3) * 32 + j) * 1024) + b * 128 + kk]);
            } else {
                if (j > 0) v = ld_f32x2(&Hn[(((i & 3) * 32 + (j - 1)) * 1024) + b * 128 + (kk - 128)]);
            }
            hin[b * 256 + kk]     = v.x;
            hin[b * 256 + kk + 1] = v.y;
        }
        __syncthreads();
        {
            const float* hb = hin + ks * 32;
            float acc[4][8];
            #pragma unroll
            for (int a = 0; a < 4; a++)
                #pragma unroll
                for (int b = 0; b < 8; b++) acc[a][b] = 0.f;
            #pragma unroll
            for (int cc = 0; cc < 8; cc++) {
                #pragma unroll
                for (int b = 0; b < 8; b++) {
                    float4 h = *(const float4*)(hb + b * 256 + cc * 4);
                    #pragma unroll
                    for (int a = 0; a < 4; a++)
                        acc[a][b] += w[a][cc].x * h.x + w[a][cc].y * h.y
                                   + w[a][cc].z * h.z + w[a][cc].w * h.w;
                }
            }
            #pragma unroll
            for (int a = 0; a < 4; a++)
                #pragma unroll
                for (int b = 0; b < 8; b++)
                    red[tid * 33 + a * 8 + b] = acc[a][b];
        }
        __syncthreads();
        float* GRow = Gates + i * 16384 + (j & 1) * 8192;
        #pragma unroll
        for (int q = 0; q < 4; q++) {
            const int oo = tid + q * 256;
            const int b = oo >> 7, g = oo & 127;
            const int gg2 = g >> 2, a2 = g & 3;
            float s = 0.f;
            #pragma unroll
            for (int k2 = 0; k2 < 8; k2++)
                s += red[(k2 * 32 + gg2) * 33 + a2 * 8 + b];
            s += Pproj[i * 8192 + b * 1024 + c * 128 + g]
               + ld_f32(&Hypproj[j * 8192 + b * 1024 + c * 128 + g]);
            st_f32(&GRow[b * 1024 + c * 128 + g], s);
        }
        drain_vmem();
        __syncthreads();
        if (tid == 0) st_flag_relaxed(&GateF[(i * 8 + c) * 32], BASE + (unsigned)(j + 1));

        // ---- wait all gate chunks of this row ----
        if (tid < 8) wait_ge(&GateF[(i * 8 + tid) * 32], (unsigned)(j + 1));
        __syncthreads();

        // ---- Phase B: elementwise (pair loads) + condense ----
        float* stc = red;           // c_new [8][256]
        float* sth = red + 2048;    // h_new [8][256]
        #pragma unroll
        for (int rep = 0; rep < 4; rep++) {
            int idx = rep * 256 + tid;              // 0..1023
            int b = idx >> 7, tp = (idx & 127) * 2; // even t, [0,256)
            const float* Gb = GRow + b * 1024;
            float2 gi = ld_f32x2(Gb + tp);
            float2 gf = ld_f32x2(Gb + 256 + tp);
            float2 gc = ld_f32x2(Gb + 512 + tp);
            float2 go = ld_f32x2(Gb + 768 + tp);
            float2 cin = make_float2(0.f, 0.f);
            if (tp < 128) {
                if (i > 0) cin = ld_f32x2(&Cn[((((i - 1) & 3) * 32 + j) * 1024) + b * 128 + tp]);
            } else {
                if (j > 0) cin = ld_f32x2(&Cn[(((i & 3) * 32 + (j - 1)) * 1024) + b * 128 + (tp - 128)]);
            }
            float cn0 = sigm(gf.x) * cin.x + sigm(gi.x) * tanh_fast(gc.x);
            float cn1 = sigm(gf.y) * cin.y + sigm(gi.y) * tanh_fast(gc.y);
            float hn0 = sigm(go.x) * tanh_fast(cn0);
            float hn1 = sigm(go.y) * tanh_fast(cn1);
            stc[b * 256 + tp] = cn0; stc[b * 256 + tp + 1] = cn1;
            sth[b * 256 + tp] = hn0; sth[b * 256 + tp + 1] = hn1;
        }
        __syncthreads();
        {
            const int r = tid & 31, b = tid >> 5;
            const int row = c * 16 + (r & 15);
            const float* src; const float* Wm; float bias; float* dst;
            if (r < 16) { src = sth; Wm = W_ch; bias = b_ch[row];
                          dst = &Hn[(((i & 3) * 32 + j) * 1024) + b * 128 + row]; }
            else        { src = stc; Wm = W_cc; bias = b_cc[row];
                          dst = &Cn[(((i & 3) * 32 + j) * 1024) + b * 128 + row]; }
            const float* wrow = Wm + row * 256;
            const float* x = src + b * 256;
            float a2 = bias;
            for (int k = 0; k < 256; k += 4) {
                float4 wv = *(const float4*)(wrow + k);
                float4 xv = *(const float4*)(x + k);
                a2 += wv.x * xv.x + wv.y * xv.y + wv.z * xv.z + wv.w * xv.w;
            }
            st_f32(dst, a2);
        }
        drain_vmem();
        __syncthreads();
        if (tid == 0) st_flag_relaxed(&HF[(i * 8 + c) * 32], BASE + (unsigned)(j + 1));
    }

    // ================= Final MLP + softmax (block i=31, c=0) =================
    if (bid == 31) {
        if (tid < 8) wait_ge(&HF[(31 * 8 + tid) * 32], 32u);
        __syncthreads();
        float* s1 = red;
        float* s2 = red + 1024;
        for (int idx = tid; idx < 1024; idx += 256)
            s1[idx] = ld_f32(&Hn[(((31 & 3) * 32 + 31) * 1024) + idx]);
        __syncthreads();
        for (int idx = tid; idx < 1024; idx += 256) {
            int b = idx >> 7, o = idx & 127;
            float a = b1[o];
            const float* wr = W1 + o * 128; const float* x = s1 + b * 128;
            for (int k = 0; k < 128; k++) a += wr[k] * x[k];
            s2[idx] = fmaxf(a, 0.f);
        }
        __syncthreads();
        for (int idx = tid; idx < 1024; idx += 256) {
            int b = idx >> 7, o = idx & 127;
            float a = b2[o];
            const float* wr = W2 + o * 128; const float* x = s2 + b * 128;
            for (int k = 0; k < 128; k++) a += wr[k] * x[k];
            s1[idx] = fmaxf(a, 0.f);
        }
        __syncthreads();
        if (tid < 8) {
            const int b = tid;
            float lg[3];
            for (int cc = 0; cc < 3; cc++) {
                float a = b3[cc];
                const float* wr = W3 + cc * 128; const float* x = s1 + b * 128;
                for (int k = 0; k < 128; k++) a += wr[k] * x[k];
                lg[cc] = a;
            }
            float m = fmaxf(lg[0], fmaxf(lg[1], lg[2]));
            float e0 = expf(lg[0] - m), e1 = expf(lg[1] - m), e2 = expf(lg[2] - m);
            float s = e0 + e1 + e2;
            out[b * 3 + 0] = e0 / s;
            out[b * 3 + 1] = e1 / s;
            out[b * 3 + 2] = e2 / s;
        }
    }
}

extern "C" void kernel_launch(void* const* d_in, const int* in_sizes, int n_in,
                              void* d_out, int out_size, void* d_ws, size_t ws_size,
                              hipStream_t stream) {
    const int*   premise    = (const int*)d_in[0];
    const int*   hypothesis = (const int*)d_in[1];
    const float* emb        = (const float*)d_in[2];
    const float* W_ih       = (const float*)d_in[3];
    const float* b_ih       = (const float*)d_in[4];
    const float* W_hh       = (const float*)d_in[5];
    const float* b_hh       = (const float*)d_in[6];
    const float* W_ch       = (const float*)d_in[7];
    const float* b_ch       = (const float*)d_in[8];
    const float* W_cc       = (const float*)d_in[9];
    const float* b_cc       = (const float*)d_in[10];
    const float* W1         = (const float*)d_in[11];
    const float* b1         = (const float*)d_in[12];
    const float* W2         = (const float*)d_in[13];
    const float* b2         = (const float*)d_in[14];
    const float* W3         = (const float*)d_in[15];
    const float* b3         = (const float*)d_in[16];
    float* out = (float*)d_out;
    float* ws  = (float*)d_ws;

    (void)in_sizes; (void)n_in; (void)out_size; (void)ws_size;

    grid_lstm_kernel<<<dim3(256), dim3(256), 0, stream>>>(
        premise, hypothesis, emb, W_ih, b_ih, W_hh, b_hh,
        W_ch, b_ch, W_cc, b_cc, W1, b1, W2, b2, W3, b3, out, ws);
}